// Round 10
// baseline (11825.265 us; speedup 1.0000x reference)
//
#include <hip/hip_runtime.h>
#include <hip/hip_bf16.h>
#include <math.h>

// ---------------------------------------------------------------------------
// BiLSTM-CRF, fp32 end-to-end.
// Sizes: B=64 T=256 CHAR_E=256 POS_E=128 Hp=128, Hm=256, Dm=640, LBL=20.
// R10: main_rec = ONE BLOCK PER (b,dir) CHAIN, 1024 threads, NO cross-block
// exchange (R2-R9 showed an irreducible ~1us/step L3 round trip for any
// split-chain scheme). 1024 thr = 16 waves = 4 waves/SIMD -> 512-reg/lane
// unified budget: all 64 f4 (256 floats) of each thread's gate row pinned
// via asm-opaque PIN4 (cures loop-invariant-load sinking, R7-proven).
// h (256 floats) is block-local LDS. Step = matvec + gates + 2 barriers.
// ---------------------------------------------------------------------------

#define Bsz 64
#define Tsz 256
#define NROW 16384        // B*T

__device__ __forceinline__ float sigm(float x) { return 1.f / (1.f + expf(-x)); }

#define PIN4(v) asm volatile("" : "+v"((v).x), "+v"((v).y), "+v"((v).z), "+v"((v).w))

// ------------------------- gather: embeddings --------------------------------
__global__ __launch_bounds__(256) void gather_kernel(
    const int* __restrict__ ci, const int* __restrict__ pi, const int* __restrict__ ti,
    const float* __restrict__ ce, const float* __restrict__ pe, const float* __restrict__ te,
    float* __restrict__ tbuf, float* __restrict__ emb) {
  int gid = blockIdx.x * 256 + threadIdx.x;     // NROW*128 threads
  int m = gid >> 7, s = gid & 127;
  if (s < 32) {
    ((float4*)&tbuf[(size_t)m * 128])[s] = ((const float4*)&te[(size_t)ti[m] * 128])[s];
  } else if (s < 96) {
    ((float4*)&emb[(size_t)m * 640])[s - 32] = ((const float4*)&ce[(size_t)ci[m] * 256])[s - 32];
  } else {
    ((float4*)&emb[(size_t)m * 640 + 256])[s - 96] = ((const float4*)&pe[(size_t)pi[m] * 128])[s - 96];
  }
}

// ------------------- fp32 tiled GEMM: C[m,n] = A[m,:].B[n,:] + bias[n] -------
#define GBM 128
#define GBN 128
#define GBK 16
__global__ __launch_bounds__(256) void gemm_nt(
    const float* __restrict__ A, int lda,
    const float* __restrict__ B, int ldb,
    const float* __restrict__ bias,
    float* __restrict__ C, int ldc, int col0, int K) {
  __shared__ __align__(16) float As[GBK][GBM + 4];
  __shared__ __align__(16) float Bs[GBK][GBN + 4];
  const int tid = threadIdx.x;
  const int tx = tid & 15, ty = tid >> 4;
  const int m0 = blockIdx.y * GBM, n0 = blockIdx.x * GBN;
  float acc[8][8] = {};
  for (int k0 = 0; k0 < K; k0 += GBK) {
#pragma unroll
    for (int r = 0; r < 2; ++r) {
      int fi = tid + r * 256;           // 512 float4 per tile
      int row = fi >> 2, kq = (fi & 3) * 4;
      float4 v = *(const float4*)&A[(size_t)(m0 + row) * lda + k0 + kq];
      As[kq + 0][row] = v.x; As[kq + 1][row] = v.y; As[kq + 2][row] = v.z; As[kq + 3][row] = v.w;
      float4 w = *(const float4*)&B[(size_t)(n0 + row) * ldb + k0 + kq];
      Bs[kq + 0][row] = w.x; Bs[kq + 1][row] = w.y; Bs[kq + 2][row] = w.z; Bs[kq + 3][row] = w.w;
    }
    __syncthreads();
#pragma unroll
    for (int kk = 0; kk < GBK; ++kk) {
      float4 a0 = *(const float4*)&As[kk][ty * 8];
      float4 a1 = *(const float4*)&As[kk][ty * 8 + 4];
      float4 b0 = *(const float4*)&Bs[kk][tx * 8];
      float4 b1 = *(const float4*)&Bs[kk][tx * 8 + 4];
      float av[8] = {a0.x,a0.y,a0.z,a0.w,a1.x,a1.y,a1.z,a1.w};
      float bv[8] = {b0.x,b0.y,b0.z,b0.w,b1.x,b1.y,b1.z,b1.w};
#pragma unroll
      for (int i = 0; i < 8; ++i)
#pragma unroll
        for (int jj = 0; jj < 8; ++jj) acc[i][jj] = fmaf(av[i], bv[jj], acc[i][jj]);
    }
    __syncthreads();
  }
#pragma unroll
  for (int i = 0; i < 8; ++i) {
    size_t m = m0 + ty * 8 + i;
    int nb = n0 + tx * 8;
    float4 o0 = {acc[i][0] + bias[nb+0], acc[i][1] + bias[nb+1], acc[i][2] + bias[nb+2], acc[i][3] + bias[nb+3]};
    float4 o1 = {acc[i][4] + bias[nb+4], acc[i][5] + bias[nb+5], acc[i][6] + bias[nb+6], acc[i][7] + bias[nb+7]};
    *(float4*)&C[m * ldc + col0 + nb]     = o0;
    *(float4*)&C[m * ldc + col0 + nb + 4] = o1;
  }
}

// --------------------------- pos BiLSTM recurrence ---------------------------
// 128 blocks (b, dir). 512 threads = 512 gate rows; Whh [512][128] pinned via
// asm-opaque (cures compiler loop-invariant-load sinking). R7-proven.
__global__ __launch_bounds__(512, 2) void pos_rec(
    const int* __restrict__ lengths, const float* __restrict__ gpos,
    const float* __restrict__ Wf, const float* __restrict__ Wb,
    float* __restrict__ emb) {
  const int blk = blockIdx.x;
  const int b = blk >> 1, dir = blk & 1;
  const int j = threadIdx.x;
  const int gc = j >> 7;
  const int len = lengths[b];
  const float* W = dir ? Wb : Wf;
  __shared__ __align__(16) float h[128];
  __shared__ float gbuf[512];
  float4 w4[32];
#pragma unroll
  for (int i = 0; i < 32; ++i) w4[i] = *(const float4*)&W[(size_t)j * 128 + i * 4];
#pragma unroll
  for (int i = 0; i < 32; ++i) PIN4(w4[i]);
  float c = 0.f;
  if (j < 128) h[j] = 0.f;
  __syncthreads();
  int idx0 = dir ? (len - 1) : 0;
  float gcur = gpos[((size_t)(b * Tsz + idx0)) * 1024 + dir * 512 + j];
  for (int t = 0; t < len; ++t) {
    const int idx = dir ? (len - 1 - t) : t;
    const int tn = (t + 1 < len) ? t + 1 : t;
    const int idxn = dir ? (len - 1 - tn) : tn;
    float gnext = gpos[((size_t)(b * Tsz + idxn)) * 1024 + dir * 512 + j];
    float acc = gcur;
    const float4* h4 = (const float4*)h;
#pragma unroll
    for (int i = 0; i < 32; ++i) {
      float4 hh = h4[i];
      acc = fmaf(hh.x, w4[i].x, acc); acc = fmaf(hh.y, w4[i].y, acc);
      acc = fmaf(hh.z, w4[i].z, acc); acc = fmaf(hh.w, w4[i].w, acc);
    }
    gbuf[j] = (gc == 2) ? tanhf(acc) : sigm(acc);
    __syncthreads();
    if (j < 128) {
      float si = gbuf[j], sf = gbuf[128 + j], tg = gbuf[256 + j], so = gbuf[384 + j];
      c = sf * c + si * tg;
      float hn = so * tanhf(c);
      h[j] = hn;
      emb[((size_t)(b * Tsz + idx)) * 640 + 384 + dir * 128 + j] = hn;
    }
    __syncthreads();
    gcur = gnext;
  }
}

// --------------------------- main BiLSTM recurrence --------------------------
// 128 blocks = (b, dir) chains. 1024 threads = 1024 gate rows (i,f,g,o in
// 256-row groups). All 256 weights/thread (64 f4) PINNED in the unified
// 512-reg/lane budget (16 waves/block -> 4 waves/SIMD -> 512 regs/lane).
// h[256] is block-local LDS: NO cross-block exchange, no atomics, no polls.
#define MW_F4 64
__global__ __launch_bounds__(1024) void main_rec(
    const int* __restrict__ lengths, const float* __restrict__ gmain,
    const float* __restrict__ Wf, const float* __restrict__ Wb,
    float* __restrict__ lstm_out) {
  __shared__ __align__(16) float hbuf[256];
  __shared__ float gbuf[1024];
  const int blk = blockIdx.x;
  const int b = blk >> 1, dir = blk & 1;
  const int r = threadIdx.x;                 // gate row 0..1023
  const int gc = r >> 8;                     // gate class: 0=i 1=f 2=g 3=o
  const int len = lengths[b];
  const float* Wr = (dir ? Wb : Wf) + (size_t)r * 256;

  float4 wv[MW_F4];
#pragma unroll
  for (int i = 0; i < MW_F4; ++i) wv[i] = *(const float4*)&Wr[i * 4];
#pragma unroll
  for (int i = 0; i < MW_F4; ++i) PIN4(wv[i]);

  float c = 0.f;
  if (r < 256) hbuf[r] = 0.f;
  __syncthreads();

  const int idx0 = dir ? (len - 1) : 0;
  float gcur = gmain[((size_t)(b * Tsz + idx0)) * 2048 + dir * 1024 + r];
  for (int t = 0; t < len; ++t) {
    const int idx = dir ? (len - 1 - t) : t;
    const int tn = (t + 1 < len) ? t + 1 : t;
    const int idxn = dir ? (len - 1 - tn) : tn;
    float gnext = gmain[((size_t)(b * Tsz + idxn)) * 2048 + dir * 1024 + r];
    // matvec over full h (t=0: h=0 contributes nothing)
    float acc = gcur;
    const float4* hb4 = (const float4*)hbuf;
#pragma unroll
    for (int i = 0; i < MW_F4; ++i) {
      float4 hh = hb4[i], w = wv[i];
      acc = fmaf(hh.x, w.x, acc); acc = fmaf(hh.y, w.y, acc);
      acc = fmaf(hh.z, w.z, acc); acc = fmaf(hh.w, w.w, acc);
    }
    gbuf[r] = (gc == 2) ? tanhf(acc) : sigm(acc);
    __syncthreads();
    if (r < 256) {
      float si = gbuf[r], sf = gbuf[256 + r], tg = gbuf[512 + r], so = gbuf[768 + r];
      c = sf * c + si * tg;
      float hn = so * tanhf(c);
      hbuf[r] = hn;
      lstm_out[((size_t)(b * Tsz + idx)) * 512 + dir * 256 + r] = hn;
    }
    __syncthreads();
    gcur = gnext;
  }
}

// ------------------------------- emit GEMM -----------------------------------
__global__ __launch_bounds__(256) void emit_kernel(
    const float* __restrict__ lstm_out, const float* __restrict__ Wout,
    const float* __restrict__ bout, float* __restrict__ emit) {
  int gid = blockIdx.x * 256 + threadIdx.x;      // NROW*32 threads
  int m = gid >> 5, j = gid & 31;
  if (j >= 20) return;
  const float4* xr = (const float4*)&lstm_out[(size_t)m * 512];
  const float4* wr = (const float4*)&Wout[(size_t)j * 512];
  float acc = bout[j];
#pragma unroll 8
  for (int i = 0; i < 128; ++i) {
    float4 x = xr[i], w = wr[i];
    acc += x.x * w.x + x.y * w.y + x.z * w.z + x.w * w.w;
  }
  emit[(size_t)m * 20 + j] = acc;
}

// ------------------------------- Viterbi -------------------------------------
__global__ __launch_bounds__(64) void viterbi_kernel(
    const int* __restrict__ lengths, const float* __restrict__ emit,
    const float* __restrict__ trans, int* __restrict__ out) {
  const int b = blockIdx.x, j = threadIdx.x;
  const int len = lengths[b];
  __shared__ float tr[400];
  __shared__ float alpha[20];
  __shared__ float fin[20];
  __shared__ unsigned char bp[256][20];
  for (int i = j; i < 400; i += 64) tr[i] = trans[i];
  __syncthreads();
  if (j < 20) alpha[j] = tr[18 * 20 + j] + emit[(size_t)(b * Tsz) * 20 + j];
  __syncthreads();
  for (int t = 1; t < len; ++t) {
    float best = 0.f; int bi = 0;
    if (j < 20) {
      best = alpha[0] + tr[j];
#pragma unroll
      for (int i = 1; i < 20; ++i) {
        float s = alpha[i] + tr[i * 20 + j];
        if (s > best) { best = s; bi = i; }
      }
      best += emit[((size_t)(b * Tsz + t)) * 20 + j];
    }
    __syncthreads();
    if (j < 20) { alpha[j] = best; bp[t][j] = (unsigned char)bi; }
    __syncthreads();
  }
  if (j < 20) fin[j] = alpha[j] + tr[j * 20 + 19];
  __syncthreads();
  if (j == 0) {
    float best = fin[0]; int tag = 0;
    for (int i = 1; i < 20; ++i) if (fin[i] > best) { best = fin[i]; tag = i; }
    out[b * Tsz + len - 1] = tag;
    for (int t = len - 1; t >= 1; --t) { tag = bp[t][tag]; out[b * Tsz + t - 1] = tag; }
  }
  for (int t = len + j; t < Tsz; t += 64) out[b * Tsz + t] = 0;
}

// ------------------------------- launcher ------------------------------------
extern "C" void kernel_launch(void* const* d_in, const int* in_sizes, int n_in,
                              void* d_out, int out_size, void* d_ws, size_t ws_size,
                              hipStream_t stream) {
  const int*   char_in = (const int*)d_in[0];
  const int*   pos_in  = (const int*)d_in[1];
  const int*   tag_in  = (const int*)d_in[2];
  const int*   lengths = (const int*)d_in[3];
  // d_in[4] = mask: recomputed from lengths, unused.
  const float* ce      = (const float*)d_in[5];
  const float* pe      = (const float*)d_in[6];
  const float* te      = (const float*)d_in[7];
  const float* pWih_f  = (const float*)d_in[8];
  const float* pWhh_f  = (const float*)d_in[9];
  const float* pb_f    = (const float*)d_in[10];
  const float* pWih_b  = (const float*)d_in[11];
  const float* pWhh_b  = (const float*)d_in[12];
  const float* pb_b    = (const float*)d_in[13];
  const float* mWih_f  = (const float*)d_in[14];
  const float* mWhh_f  = (const float*)d_in[15];
  const float* mb_f    = (const float*)d_in[16];
  const float* mWih_b  = (const float*)d_in[17];
  const float* mWhh_b  = (const float*)d_in[18];
  const float* mb_b    = (const float*)d_in[19];
  const float* W_out   = (const float*)d_in[20];
  const float* b_out   = (const float*)d_in[21];
  const float* trans   = (const float*)d_in[22];

  float* ws = (float*)d_ws;
  const size_t EMB     = 0;                          // 16384*640
  const size_t LSTMOUT = EMB + (size_t)NROW * 640;   // 16384*512
  const size_t EMIT    = LSTMOUT + (size_t)NROW * 512;
  const size_t TBUF    = EMIT + (size_t)NROW * 20;   // 16384*128
  const size_t GPOS    = TBUF + (size_t)NROW * 128;  // 16384*1024
  const size_t GMAIN   = TBUF;                       // 16384*2048 (overlaps)

  gather_kernel<<<8192, 256, 0, stream>>>(char_in, pos_in, tag_in, ce, pe, te,
                                          ws + TBUF, ws + EMB);

  gemm_nt<<<dim3(4, 128), 256, 0, stream>>>(ws + TBUF, 128, pWih_f, 128, pb_f,
                                            ws + GPOS, 1024, 0, 128);
  gemm_nt<<<dim3(4, 128), 256, 0, stream>>>(ws + TBUF, 128, pWih_b, 128, pb_b,
                                            ws + GPOS, 1024, 512, 128);

  pos_rec<<<128, 512, 0, stream>>>(lengths, ws + GPOS, pWhh_f, pWhh_b, ws + EMB);

  gemm_nt<<<dim3(8, 128), 256, 0, stream>>>(ws + EMB, 640, mWih_f, 640, mb_f,
                                            ws + GMAIN, 2048, 0, 640);
  gemm_nt<<<dim3(8, 128), 256, 0, stream>>>(ws + EMB, 640, mWih_b, 640, mb_b,
                                            ws + GMAIN, 2048, 1024, 640);

  main_rec<<<128, 1024, 0, stream>>>(lengths, ws + GMAIN, mWhh_f, mWhh_b,
                                     ws + LSTMOUT);

  emit_kernel<<<2048, 256, 0, stream>>>(ws + LSTMOUT, W_out, b_out, ws + EMIT);

  viterbi_kernel<<<64, 64, 0, stream>>>(lengths, ws + EMIT, trans, (int*)d_out);
}

// Round 11
// 1744.252 us; speedup vs baseline: 6.7796x; 6.7796x over previous
//
#include <hip/hip_runtime.h>
#include <hip/hip_bf16.h>
#include <math.h>

// ---------------------------------------------------------------------------
// BiLSTM-CRF, fp32 end-to-end.
// Sizes: B=64 T=256 CHAR_E=256 POS_E=128 Hp=128, Hm=256, Dm=640, LBL=20.
// R11: (1) main_rec REVERTED to R7-exact (637us proven; R10's 1-block design
// needed 1MB regs vs the 512KB/CU register file -> 15GB scratch spill.
// Lesson: VGPR pool = 512 regs/lane/SIMD; budget = 512/waves_per_simd).
// (2) gemm_nt: double-buffered LDS, 1 barrier/tile, prefetch-into-regs
// (was 2 barriers + no overlap -> ~51 TF; same k-order = bit-identical).
// ---------------------------------------------------------------------------

#define Bsz 64
#define Tsz 256
#define NROW 16384        // B*T

__device__ __forceinline__ float sigm(float x) { return 1.f / (1.f + expf(-x)); }

#define PIN4(v) asm volatile("" : "+v"((v).x), "+v"((v).y), "+v"((v).z), "+v"((v).w))

// ------------------------- gather: embeddings --------------------------------
__global__ __launch_bounds__(256) void gather_kernel(
    const int* __restrict__ ci, const int* __restrict__ pi, const int* __restrict__ ti,
    const float* __restrict__ ce, const float* __restrict__ pe, const float* __restrict__ te,
    float* __restrict__ tbuf, float* __restrict__ emb) {
  int gid = blockIdx.x * 256 + threadIdx.x;     // NROW*128 threads
  int m = gid >> 7, s = gid & 127;
  if (s < 32) {
    ((float4*)&tbuf[(size_t)m * 128])[s] = ((const float4*)&te[(size_t)ti[m] * 128])[s];
  } else if (s < 96) {
    ((float4*)&emb[(size_t)m * 640])[s - 32] = ((const float4*)&ce[(size_t)ci[m] * 256])[s - 32];
  } else {
    ((float4*)&emb[(size_t)m * 640 + 256])[s - 96] = ((const float4*)&pe[(size_t)pi[m] * 128])[s - 96];
  }
}

// ------------------- fp32 tiled GEMM: C[m,n] = A[m,:].B[n,:] + bias[n] -------
// Double-buffered LDS, one barrier per k-tile. K must be a multiple of 16.
#define GBM 128
#define GBN 128
#define GBK 16
__global__ __launch_bounds__(256) void gemm_nt(
    const float* __restrict__ A, int lda,
    const float* __restrict__ B, int ldb,
    const float* __restrict__ bias,
    float* __restrict__ C, int ldc, int col0, int K) {
  __shared__ __align__(16) float As[2][GBK][GBM + 4];
  __shared__ __align__(16) float Bs[2][GBK][GBN + 4];
  const int tid = threadIdx.x;
  const int tx = tid & 15, ty = tid >> 4;
  const int m0 = blockIdx.y * GBM, n0 = blockIdx.x * GBN;
  const int row0 = tid >> 2, kq = (tid & 3) * 4;
  const int row1 = row0 + 64;
  const float* Ar0 = &A[(size_t)(m0 + row0) * lda + kq];
  const float* Ar1 = &A[(size_t)(m0 + row1) * lda + kq];
  const float* Br0 = &B[(size_t)(n0 + row0) * ldb + kq];
  const float* Br1 = &B[(size_t)(n0 + row1) * ldb + kq];

  float acc[8][8] = {};
  float4 a0 = *(const float4*)Ar0;
  float4 a1 = *(const float4*)Ar1;
  float4 b0 = *(const float4*)Br0;
  float4 b1 = *(const float4*)Br1;
  int buf = 0;
  As[0][kq + 0][row0] = a0.x; As[0][kq + 1][row0] = a0.y; As[0][kq + 2][row0] = a0.z; As[0][kq + 3][row0] = a0.w;
  As[0][kq + 0][row1] = a1.x; As[0][kq + 1][row1] = a1.y; As[0][kq + 2][row1] = a1.z; As[0][kq + 3][row1] = a1.w;
  Bs[0][kq + 0][row0] = b0.x; Bs[0][kq + 1][row0] = b0.y; Bs[0][kq + 2][row0] = b0.z; Bs[0][kq + 3][row0] = b0.w;
  Bs[0][kq + 0][row1] = b1.x; Bs[0][kq + 1][row1] = b1.y; Bs[0][kq + 2][row1] = b1.z; Bs[0][kq + 3][row1] = b1.w;
  __syncthreads();

  for (int k0 = 0; k0 < K; k0 += GBK) {
    const bool more = (k0 + GBK) < K;
    if (more) {
      a0 = *(const float4*)(Ar0 + k0 + GBK);
      a1 = *(const float4*)(Ar1 + k0 + GBK);
      b0 = *(const float4*)(Br0 + k0 + GBK);
      b1 = *(const float4*)(Br1 + k0 + GBK);
    }
#pragma unroll
    for (int kk = 0; kk < GBK; ++kk) {
      float4 x0 = *(const float4*)&As[buf][kk][ty * 8];
      float4 x1 = *(const float4*)&As[buf][kk][ty * 8 + 4];
      float4 y0 = *(const float4*)&Bs[buf][kk][tx * 8];
      float4 y1 = *(const float4*)&Bs[buf][kk][tx * 8 + 4];
      float av[8] = {x0.x, x0.y, x0.z, x0.w, x1.x, x1.y, x1.z, x1.w};
      float bv[8] = {y0.x, y0.y, y0.z, y0.w, y1.x, y1.y, y1.z, y1.w};
#pragma unroll
      for (int i = 0; i < 8; ++i)
#pragma unroll
        for (int jj = 0; jj < 8; ++jj) acc[i][jj] = fmaf(av[i], bv[jj], acc[i][jj]);
    }
    if (more) {
      buf ^= 1;
      As[buf][kq + 0][row0] = a0.x; As[buf][kq + 1][row0] = a0.y; As[buf][kq + 2][row0] = a0.z; As[buf][kq + 3][row0] = a0.w;
      As[buf][kq + 0][row1] = a1.x; As[buf][kq + 1][row1] = a1.y; As[buf][kq + 2][row1] = a1.z; As[buf][kq + 3][row1] = a1.w;
      Bs[buf][kq + 0][row0] = b0.x; Bs[buf][kq + 1][row0] = b0.y; Bs[buf][kq + 2][row0] = b0.z; Bs[buf][kq + 3][row0] = b0.w;
      Bs[buf][kq + 0][row1] = b1.x; Bs[buf][kq + 1][row1] = b1.y; Bs[buf][kq + 2][row1] = b1.z; Bs[buf][kq + 3][row1] = b1.w;
      __syncthreads();
    }
  }
#pragma unroll
  for (int i = 0; i < 8; ++i) {
    size_t m = m0 + ty * 8 + i;
    int nb = n0 + tx * 8;
    float4 o0 = {acc[i][0] + bias[nb+0], acc[i][1] + bias[nb+1], acc[i][2] + bias[nb+2], acc[i][3] + bias[nb+3]};
    float4 o1 = {acc[i][4] + bias[nb+4], acc[i][5] + bias[nb+5], acc[i][6] + bias[nb+6], acc[i][7] + bias[nb+7]};
    *(float4*)&C[m * ldc + col0 + nb]     = o0;
    *(float4*)&C[m * ldc + col0 + nb + 4] = o1;
  }
}

// --------------------------- pos BiLSTM recurrence ---------------------------
// 128 blocks (b, dir). 512 threads = 512 gate rows; Whh [512][128] pinned via
// asm-opaque (cures compiler loop-invariant-load sinking). R7-proven.
__global__ __launch_bounds__(512, 2) void pos_rec(
    const int* __restrict__ lengths, const float* __restrict__ gpos,
    const float* __restrict__ Wf, const float* __restrict__ Wb,
    float* __restrict__ emb) {
  const int blk = blockIdx.x;
  const int b = blk >> 1, dir = blk & 1;
  const int j = threadIdx.x;
  const int gc = j >> 7;
  const int len = lengths[b];
  const float* W = dir ? Wb : Wf;
  __shared__ __align__(16) float h[128];
  __shared__ float gbuf[512];
  float4 w4[32];
#pragma unroll
  for (int i = 0; i < 32; ++i) w4[i] = *(const float4*)&W[(size_t)j * 128 + i * 4];
#pragma unroll
  for (int i = 0; i < 32; ++i) PIN4(w4[i]);
  float c = 0.f;
  if (j < 128) h[j] = 0.f;
  __syncthreads();
  int idx0 = dir ? (len - 1) : 0;
  float gcur = gpos[((size_t)(b * Tsz + idx0)) * 1024 + dir * 512 + j];
  for (int t = 0; t < len; ++t) {
    const int idx = dir ? (len - 1 - t) : t;
    const int tn = (t + 1 < len) ? t + 1 : t;
    const int idxn = dir ? (len - 1 - tn) : tn;
    float gnext = gpos[((size_t)(b * Tsz + idxn)) * 1024 + dir * 512 + j];
    float acc = gcur;
    const float4* h4 = (const float4*)h;
#pragma unroll
    for (int i = 0; i < 32; ++i) {
      float4 hh = h4[i];
      acc = fmaf(hh.x, w4[i].x, acc); acc = fmaf(hh.y, w4[i].y, acc);
      acc = fmaf(hh.z, w4[i].z, acc); acc = fmaf(hh.w, w4[i].w, acc);
    }
    gbuf[j] = (gc == 2) ? tanhf(acc) : sigm(acc);
    __syncthreads();
    if (j < 128) {
      float si = gbuf[j], sf = gbuf[128 + j], tg = gbuf[256 + j], so = gbuf[384 + j];
      c = sf * c + si * tg;
      float hn = so * tanhf(c);
      h[j] = hn;
      emb[((size_t)(b * Tsz + idx)) * 640 + 384 + dir * 128 + j] = hn;
    }
    __syncthreads();
    gcur = gnext;
  }
}

// --------------------------- main BiLSTM recurrence --------------------------
// R7-EXACT. 256 blocks: blk = b*4 + dir*2 + half; partner = blk^1.
// 512 threads = 512 gate rows of this half's 128 h-units.
// Weights per thread (256 floats): 40 f4 PINNED VGPR (k 0..159),
// 19 f4 LDS (k 160..235), 5 f4 compiler-choice (k 236..255).
// Per step: matvec(full h) -> act -> barrier ->
// w01: gates -> h -> agent-atomic store -> lstm_out -> poll partner -> barrier.
#define MR_VF4 40
#define MR_LF4 19
#define MR_TF4 5
#define HX_STRIDE 256      // ull per block (2 parity slots x 128)
__global__ __launch_bounds__(512, 2) void main_rec(
    const int* __restrict__ lengths, const float* __restrict__ gmain,
    const float* __restrict__ Wf, const float* __restrict__ Wb,
    float* __restrict__ lstm_out, unsigned long long* __restrict__ hx) {
  extern __shared__ float smem[];
  float4* wl  = (float4*)smem;                    // [MR_LF4*512] float4
  float* hbuf = smem + MR_LF4 * 512 * 4;          // 256 (full h, absolute idx)
  float* gbuf = hbuf + 256;                       // 512

  const int blk = blockIdx.x;
  const int b = blk >> 2, dir = (blk >> 1) & 1, half = blk & 1;
  const int j = threadIdx.x;
  const int gc = j >> 7, ul = j & 127;
  const int r = gc * 256 + half * 128 + ul;        // gate row in [0,1024)
  const int len = lengths[b];
  const float* Wr = (dir ? Wb : Wf) + (size_t)r * 256;

  float4 wv[MR_VF4];
#pragma unroll
  for (int i = 0; i < MR_VF4; ++i) wv[i] = *(const float4*)&Wr[i * 4];
#pragma unroll
  for (int i = 0; i < MR_VF4; ++i) PIN4(wv[i]);
#pragma unroll
  for (int i = 0; i < MR_LF4; ++i) wl[i * 512 + j] = *(const float4*)&Wr[(MR_VF4 + i) * 4];

  unsigned long long* selfD = hx + (size_t)blk * HX_STRIDE;
  unsigned long long* partD = hx + (size_t)(blk ^ 1) * HX_STRIDE;
  const int obase = dir * 256 + half * 128;

  float c = 0.f;
  if (j < 256) hbuf[j] = 0.f;
  __syncthreads();

  const int idx0 = dir ? (len - 1) : 0;
  float gcur = gmain[((size_t)(b * Tsz + idx0)) * 2048 + dir * 1024 + r];
  for (int t = 0; t < len; ++t) {
    const int idx = dir ? (len - 1 - t) : t;
    const int tn = (t + 1 < len) ? t + 1 : t;
    const int idxn = dir ? (len - 1 - tn) : tn;
    float gnext = gmain[((size_t)(b * Tsz + idxn)) * 2048 + dir * 1024 + r];
    // matvec over full h (t=0: h=0 contributes nothing)
    float acc = gcur;
    const float4* hb4 = (const float4*)hbuf;
#pragma unroll
    for (int i = 0; i < MR_VF4; ++i) {
      float4 hh = hb4[i], w = wv[i];
      acc = fmaf(hh.x, w.x, acc); acc = fmaf(hh.y, w.y, acc);
      acc = fmaf(hh.z, w.z, acc); acc = fmaf(hh.w, w.w, acc);
    }
#pragma unroll
    for (int i = 0; i < MR_LF4; ++i) {
      float4 hh = hb4[MR_VF4 + i], w = wl[i * 512 + j];
      acc = fmaf(hh.x, w.x, acc); acc = fmaf(hh.y, w.y, acc);
      acc = fmaf(hh.z, w.z, acc); acc = fmaf(hh.w, w.w, acc);
    }
#pragma unroll
    for (int i = 0; i < MR_TF4; ++i) {
      float4 hh = hb4[MR_VF4 + MR_LF4 + i];
      float4 w = *(const float4*)&Wr[(MR_VF4 + MR_LF4 + i) * 4];
      acc = fmaf(hh.x, w.x, acc); acc = fmaf(hh.y, w.y, acc);
      acc = fmaf(hh.z, w.z, acc); acc = fmaf(hh.w, w.w, acc);
    }
    gbuf[j] = (gc == 2) ? tanhf(acc) : sigm(acc);
    __syncthreads();
    if (j < 128) {
      float si = gbuf[ul], sf = gbuf[128 + ul], tg = gbuf[256 + ul], so = gbuf[384 + ul];
      c = sf * c + si * tg;
      float hn = so * tanhf(c);
      if (t + 1 < len) {
        union { float f; unsigned u; } cv; cv.f = hn;
        unsigned long long pk =
            ((unsigned long long)(unsigned)(t + 1) << 32) | (unsigned long long)cv.u;
        __hip_atomic_store(&selfD[(t & 1) * 128 + ul], pk,
                           __ATOMIC_RELAXED, __HIP_MEMORY_SCOPE_AGENT);
      }
      lstm_out[((size_t)(b * Tsz + idx)) * 512 + obase + ul] = hn;
      hbuf[half * 128 + ul] = hn;
      if (t + 1 < len) {
        unsigned long long pv; int guard = 0;
        for (;;) {
          pv = __hip_atomic_load(&partD[(t & 1) * 128 + ul],
                                 __ATOMIC_RELAXED, __HIP_MEMORY_SCOPE_AGENT);
          if ((unsigned)(pv >> 32) == (unsigned)(t + 1)) break;
          if (++guard > (1 << 22)) break;   // watchdog
          __builtin_amdgcn_s_sleep(1);
        }
        union { unsigned u; float f; } hv; hv.u = (unsigned)(pv & 0xffffffffull);
        hbuf[(half ^ 1) * 128 + ul] = hv.f;
      }
    }
    __syncthreads();
    gcur = gnext;
  }
}

// ------------------------------- emit GEMM -----------------------------------
__global__ __launch_bounds__(256) void emit_kernel(
    const float* __restrict__ lstm_out, const float* __restrict__ Wout,
    const float* __restrict__ bout, float* __restrict__ emit) {
  int gid = blockIdx.x * 256 + threadIdx.x;      // NROW*32 threads
  int m = gid >> 5, j = gid & 31;
  if (j >= 20) return;
  const float4* xr = (const float4*)&lstm_out[(size_t)m * 512];
  const float4* wr = (const float4*)&Wout[(size_t)j * 512];
  float acc = bout[j];
#pragma unroll 8
  for (int i = 0; i < 128; ++i) {
    float4 x = xr[i], w = wr[i];
    acc += x.x * w.x + x.y * w.y + x.z * w.z + x.w * w.w;
  }
  emit[(size_t)m * 20 + j] = acc;
}

// ------------------------------- Viterbi -------------------------------------
__global__ __launch_bounds__(64) void viterbi_kernel(
    const int* __restrict__ lengths, const float* __restrict__ emit,
    const float* __restrict__ trans, int* __restrict__ out) {
  const int b = blockIdx.x, j = threadIdx.x;
  const int len = lengths[b];
  __shared__ float tr[400];
  __shared__ float alpha[20];
  __shared__ float fin[20];
  __shared__ unsigned char bp[256][20];
  for (int i = j; i < 400; i += 64) tr[i] = trans[i];
  __syncthreads();
  if (j < 20) alpha[j] = tr[18 * 20 + j] + emit[(size_t)(b * Tsz) * 20 + j];
  __syncthreads();
  for (int t = 1; t < len; ++t) {
    float best = 0.f; int bi = 0;
    if (j < 20) {
      best = alpha[0] + tr[j];
#pragma unroll
      for (int i = 1; i < 20; ++i) {
        float s = alpha[i] + tr[i * 20 + j];
        if (s > best) { best = s; bi = i; }
      }
      best += emit[((size_t)(b * Tsz + t)) * 20 + j];
    }
    __syncthreads();
    if (j < 20) { alpha[j] = best; bp[t][j] = (unsigned char)bi; }
    __syncthreads();
  }
  if (j < 20) fin[j] = alpha[j] + tr[j * 20 + 19];
  __syncthreads();
  if (j == 0) {
    float best = fin[0]; int tag = 0;
    for (int i = 1; i < 20; ++i) if (fin[i] > best) { best = fin[i]; tag = i; }
    out[b * Tsz + len - 1] = tag;
    for (int t = len - 1; t >= 1; --t) { tag = bp[t][tag]; out[b * Tsz + t - 1] = tag; }
  }
  for (int t = len + j; t < Tsz; t += 64) out[b * Tsz + t] = 0;
}

// ------------------------------- launcher ------------------------------------
extern "C" void kernel_launch(void* const* d_in, const int* in_sizes, int n_in,
                              void* d_out, int out_size, void* d_ws, size_t ws_size,
                              hipStream_t stream) {
  const int*   char_in = (const int*)d_in[0];
  const int*   pos_in  = (const int*)d_in[1];
  const int*   tag_in  = (const int*)d_in[2];
  const int*   lengths = (const int*)d_in[3];
  // d_in[4] = mask: recomputed from lengths, unused.
  const float* ce      = (const float*)d_in[5];
  const float* pe      = (const float*)d_in[6];
  const float* te      = (const float*)d_in[7];
  const float* pWih_f  = (const float*)d_in[8];
  const float* pWhh_f  = (const float*)d_in[9];
  const float* pb_f    = (const float*)d_in[10];
  const float* pWih_b  = (const float*)d_in[11];
  const float* pWhh_b  = (const float*)d_in[12];
  const float* pb_b    = (const float*)d_in[13];
  const float* mWih_f  = (const float*)d_in[14];
  const float* mWhh_f  = (const float*)d_in[15];
  const float* mb_f    = (const float*)d_in[16];
  const float* mWih_b  = (const float*)d_in[17];
  const float* mWhh_b  = (const float*)d_in[18];
  const float* mb_b    = (const float*)d_in[19];
  const float* W_out   = (const float*)d_in[20];
  const float* b_out   = (const float*)d_in[21];
  const float* trans   = (const float*)d_in[22];

  float* ws = (float*)d_ws;
  const size_t EMB     = 0;                          // 16384*640
  const size_t LSTMOUT = EMB + (size_t)NROW * 640;   // 16384*512
  const size_t EMIT    = LSTMOUT + (size_t)NROW * 512;
  const size_t HX      = EMIT + (size_t)NROW * 20;   // 256 * HX_STRIDE ull
  const size_t TBUF    = HX + 256 * HX_STRIDE * 2;   // 16384*128
  const size_t GPOS    = TBUF + (size_t)NROW * 128;  // 16384*1024
  const size_t GMAIN   = TBUF;                       // 16384*2048 (overlaps)

  // clear exchange region (stale tags must never match)
  hipMemsetAsync(ws + HX, 0, 256 * HX_STRIDE * sizeof(unsigned long long), stream);

  gather_kernel<<<8192, 256, 0, stream>>>(char_in, pos_in, tag_in, ce, pe, te,
                                          ws + TBUF, ws + EMB);

  gemm_nt<<<dim3(4, 128), 256, 0, stream>>>(ws + TBUF, 128, pWih_f, 128, pb_f,
                                            ws + GPOS, 1024, 0, 128);
  gemm_nt<<<dim3(4, 128), 256, 0, stream>>>(ws + TBUF, 128, pWih_b, 128, pb_b,
                                            ws + GPOS, 1024, 512, 128);

  pos_rec<<<128, 512, 0, stream>>>(lengths, ws + GPOS, pWhh_f, pWhh_b, ws + EMB);

  gemm_nt<<<dim3(8, 128), 256, 0, stream>>>(ws + EMB, 640, mWih_f, 640, mb_f,
                                            ws + GMAIN, 2048, 0, 640);
  gemm_nt<<<dim3(8, 128), 256, 0, stream>>>(ws + EMB, 640, mWih_b, 640, mb_b,
                                            ws + GMAIN, 2048, 1024, 640);

  // LDS: 19*512*16 (weights) + 256*4 + 512*4 = 158720 B (<= 160 KiB)
  const int SMEM = MR_LF4 * 512 * 16 + 256 * 4 + 512 * 4;
  hipFuncSetAttribute((const void*)main_rec,
                      hipFuncAttributeMaxDynamicSharedMemorySize, SMEM);
  main_rec<<<256, 512, SMEM, stream>>>(lengths, ws + GMAIN, mWhh_f, mWhh_b,
                                       ws + LSTMOUT, (unsigned long long*)(ws + HX));

  emit_kernel<<<2048, 256, 0, stream>>>(ws + LSTMOUT, W_out, b_out, ws + EMIT);

  viterbi_kernel<<<64, 64, 0, stream>>>(lengths, ws + EMIT, trans, (int*)d_out);
}